// Round 1
// 524.116 us; speedup vs baseline: 1.2357x; 1.2357x over previous
//
#include <hip/hip_runtime.h>
#include <hip/hip_bf16.h>
#include <math.h>

// Problem constants (from reference setup_inputs)
#define NNODES 100000
#define F_IN   500
#define F_MID  64
#define F_OUT  40
#define KPAD   512     // F_IN padded to multiple of 32 for MFMA
#define H2S    48      // h2 row stride (40 classes + 8 zero pad cols)

// Bucketed CSR build: 128 nodes per bucket
#define BSH    7
#define NBUCK  782     // ceil(100000 / 128)
#define EPB    8192    // edges per block in bucket kernels
#define K4CACHE 3072   // LDS edge cache per bucket (mean 2046, +20 sigma)

typedef __attribute__((ext_vector_type(8))) short short8;   // 8 bf16 = 4 VGPRs
typedef __attribute__((ext_vector_type(4))) float f32x4;    // MFMA acc

__device__ __forceinline__ unsigned short f2bf(float f) {
    union { float f; unsigned u; } c; c.f = f;
    unsigned r = c.u + 0x7FFF + ((c.u >> 16) & 1);   // round-nearest-even
    return (unsigned short)(r >> 16);
}
__device__ __forceinline__ float bf2f(unsigned short u) {
    union { unsigned v; float f; } c; c.v = ((unsigned)u) << 16; return c.f;
}

// ---------------------------------------------------------------------------
// CSR build, two-level bucket sort. All per-edge atomics are LDS-local;
// device atomics only per (tile,bucket) reservation (~150k non-hot).
// ---------------------------------------------------------------------------

// K1: per-bucket edge counts. LDS histogram, one device atomic per
// (block,bucket) with nonzero count.
__global__ __launch_bounds__(256) void bucket_count(const int* __restrict__ dst,
                                                    int* __restrict__ bcnt, int E) {
    __shared__ int h[NBUCK];
    int tid = threadIdx.x;
    for (int b = tid; b < NBUCK; b += 256) h[b] = 0;
    __syncthreads();
    int base = blockIdx.x * EPB;
#pragma unroll
    for (int j = 0; j < EPB / 256; j++) {
        int e = base + j * 256 + tid;
        if (e < E) atomicAdd(&h[dst[e] >> BSH], 1);
    }
    __syncthreads();
    for (int b = tid; b < NBUCK; b += 256) {
        int c = h[b];
        if (c) atomicAdd(&bcnt[b], c);
    }
}

// K2: exclusive scan of the 782 bucket counts (single block).
__global__ __launch_bounds__(1024) void bucket_scan(const int* __restrict__ bcnt,
                                                    int* __restrict__ bstart,
                                                    int* __restrict__ bcur, int E) {
    __shared__ int wsum[16];
    int t = threadIdx.x, lane = t & 63, w = t >> 6;
    int v = (t < NBUCK) ? bcnt[t] : 0;
    int s = v;
#pragma unroll
    for (int off = 1; off < 64; off <<= 1) {
        int u = __shfl_up(s, off, 64);
        if (lane >= off) s += u;
    }
    if (lane == 63) wsum[w] = s;
    __syncthreads();
    if (w == 0) {
        int ws = (lane < 16) ? wsum[lane] : 0;
#pragma unroll
        for (int off = 1; off < 16; off <<= 1) {
            int u = __shfl_up(ws, off, 64);
            if (lane >= off) ws += u;
        }
        if (lane < 16) wsum[lane] = ws;
    }
    __syncthreads();
    int excl = s - v + ((w > 0) ? wsum[w - 1] : 0);
    if (t < NBUCK) { bstart[t] = excl; bcur[t] = excl; }
    if (t == 0) bstart[NBUCK] = E;
}

// K3: scatter edges into bucket-contiguous staging. One returning device
// atomic per (block,bucket); per-edge ranks via LDS atomics. Payload packed
// as (local_node << 17) | src  (src < 2^17, local_node < 128).
__global__ __launch_bounds__(256) void bucket_scatter(const int* __restrict__ src,
                                                      const int* __restrict__ dst,
                                                      int* __restrict__ bcur,
                                                      int* __restrict__ stage, int E) {
    __shared__ int h[NBUCK];
    __shared__ int lcur[NBUCK];
    int tid = threadIdx.x;
    for (int b = tid; b < NBUCK; b += 256) h[b] = 0;
    __syncthreads();
    int base = blockIdx.x * EPB;
#pragma unroll
    for (int j = 0; j < EPB / 256; j++) {
        int e = base + j * 256 + tid;
        if (e < E) atomicAdd(&h[dst[e] >> BSH], 1);
    }
    __syncthreads();
    // Rotate flush order per block so concurrent blocks hit different
    // cache lines of bcur (reduces same-line atomic serialization).
    int rot = (blockIdx.x * 97) % NBUCK;
    for (int i = tid; i < NBUCK; i += 256) {
        int b = i + rot; if (b >= NBUCK) b -= NBUCK;
        int c = h[b];
        lcur[b] = c ? atomicAdd(&bcur[b], c) : 0;
    }
    __syncthreads();
#pragma unroll
    for (int j = 0; j < EPB / 256; j++) {
        int e = base + j * 256 + tid;
        if (e < E) {
            int d = dst[e];
            int pos = atomicAdd(&lcur[d >> BSH], 1);
            stage[pos] = ((d & 127) << 17) | src[e];
        }
    }
}

// K4: one block per bucket. LDS node histogram -> local scan (+1 self-loop
// per node) gives row_start analytically; LDS cursors scatter edges into a
// contiguous ~8.6KB csr window. Also writes dinv and self-loop entries.
__global__ __launch_bounds__(256) void bucket_fill(const int* __restrict__ stage,
                                                   const int* __restrict__ bstart,
                                                   int* __restrict__ row_start,
                                                   float* __restrict__ dinv,
                                                   int* __restrict__ csr_src, int E) {
    __shared__ int cnt[128];
    __shared__ int wtot[2];
    __shared__ int cache[K4CACHE];
    int tid = threadIdx.x;
    int b = blockIdx.x;
    int s0 = bstart[b], s1 = bstart[b + 1];
    int nE = s1 - s0;
    if (tid < 128) cnt[tid] = 0;
    __syncthreads();
    bool cached = (nE <= K4CACHE);
    for (int i = tid; i < nE; i += 256) {
        int v = stage[s0 + i];
        if (cached) cache[i] = v;
        atomicAdd(&cnt[v >> 17], 1);
    }
    __syncthreads();
    int n = (b << BSH) + tid;
    bool valid = (tid < 128) && (n < NNODES);
    int c = (tid < 128) ? cnt[tid] : 0;
    int add = valid ? (c + 1) : 0;        // +1 self-loop per valid node
    int s = add;
    int lane = tid & 63;
#pragma unroll
    for (int off = 1; off < 64; off <<= 1) {
        int u = __shfl_up(s, off, 64);
        if (lane >= off) s += u;
    }
    if (tid < 128 && lane == 63) wtot[tid >> 6] = s;
    __syncthreads();
    int excl = s - add + ((tid >= 64 && tid < 128) ? wtot[0] : 0);
    // edges before this bucket = s0; self-loops before = 128*b
    int basep = s0 + (b << BSH) + excl;
    if (valid) {
        row_start[n] = basep;
        dinv[n] = rsqrtf((float)(c + 1));
        csr_src[basep] = n;               // self-loop first
        cnt[tid] = basep + 1;             // reuse as global-position cursor
    }
    if (b == NBUCK - 1 && tid == 0) row_start[NNODES] = E + NNODES;
    __syncthreads();
    for (int i = tid; i < nE; i += 256) {
        int v = cached ? cache[i] : stage[s0 + i];
        int pos = atomicAdd(&cnt[v >> 17], 1);
        csr_src[pos] = v & 0x1FFFF;
    }
}

// ---------------------------------------------------------------------------
// W1 -> bf16, transposed, K padded: W1T[n][k], n<64, k<512
// ---------------------------------------------------------------------------
__global__ void w1t_prep(const float* __restrict__ W1, unsigned short* __restrict__ W1T) {
    int idx = blockIdx.x * blockDim.x + threadIdx.x;   // 64*512
    if (idx >= F_MID * KPAD) return;
    int n = idx >> 9;          // /512
    int k = idx & (KPAD - 1);
    float v = (k < F_IN) ? W1[k * F_MID + n] : 0.f;
    W1T[idx] = f2bf(v);
}

// W2 -> bf16, transposed, padded: W2T[col][k], col<48 (40 real), k<64
__global__ void w2t_prep(const float* __restrict__ W2, unsigned short* __restrict__ W2T) {
    int idx = blockIdx.x * blockDim.x + threadIdx.x;   // 48*64
    if (idx >= H2S * F_MID) return;
    int c = idx >> 6;
    int k = idx & 63;
    float v = (c < F_OUT) ? W2[k * F_OUT + c] : 0.f;
    W2T[idx] = f2bf(v);
}

// ---------------------------------------------------------------------------
// GEMM1 (bf16 MFMA): h1b[100000,64](bf16) = (X @ W1) * dinv[row]
// ---------------------------------------------------------------------------
__global__ __launch_bounds__(256) void gemm1_kernel(const float* __restrict__ X,
                                                    const unsigned short* __restrict__ W1T,
                                                    const float* __restrict__ dinv,
                                                    unsigned short* __restrict__ h1b) {
    const int BM = 128, BK = 32;
    __shared__ __align__(16) unsigned short A_lds[BM][BK];   // 8 KB
    __shared__ __align__(16) unsigned short B_lds[F_MID][BK]; // 4 KB

    int tid  = threadIdx.x;
    int wave = tid >> 6;
    int lane = tid & 63;
    int block_row = blockIdx.x * BM;

    int ar = tid >> 1, ah = tid & 1;
    int agr = block_row + ar;
    if (agr >= NNODES) agr = NNODES - 1;          // clamp (dup row, stores guarded)
    const float* xrow = X + (size_t)agr * F_IN;
    int bn = tid >> 2, bc = tid & 3;

    int mcol = lane & 15, quad = lane >> 4;

    f32x4 acc[2][4];
#pragma unroll
    for (int t = 0; t < 2; t++)
#pragma unroll
        for (int c = 0; c < 4; c++) {
            f32x4 z = {0.f, 0.f, 0.f, 0.f};
            acc[t][c] = z;
        }

    float4 apf[4];
    uint4  bpf;
    auto load_tile = [&](int ks) {
#pragma unroll
        for (int i = 0; i < 4; i++) {
            int kg = ks * BK + ah * 16 + i * 4;
            if (kg < F_IN) apf[i] = *(const float4*)(xrow + kg);
            else           apf[i] = make_float4(0.f, 0.f, 0.f, 0.f);
        }
        bpf = *(const uint4*)(W1T + (size_t)bn * KPAD + ks * BK + bc * 8);
    };

    load_tile(0);

    const int NK = KPAD / BK;   // 16
    for (int ks = 0; ks < NK; ks++) {
        unsigned pk[8];
#pragma unroll
        for (int i = 0; i < 4; i++) {
            pk[2 * i]     = (unsigned)f2bf(apf[i].x) | ((unsigned)f2bf(apf[i].y) << 16);
            pk[2 * i + 1] = (unsigned)f2bf(apf[i].z) | ((unsigned)f2bf(apf[i].w) << 16);
        }
        *(uint4*)&A_lds[ar][ah * 16]     = make_uint4(pk[0], pk[1], pk[2], pk[3]);
        *(uint4*)&A_lds[ar][ah * 16 + 8] = make_uint4(pk[4], pk[5], pk[6], pk[7]);
        *(uint4*)&B_lds[bn][bc * 8] = bpf;
        __syncthreads();

        if (ks + 1 < NK) load_tile(ks + 1);

        short8 a0 = *(const short8*)&A_lds[wave * 32 + mcol][quad * 8];
        short8 a1 = *(const short8*)&A_lds[wave * 32 + 16 + mcol][quad * 8];
        short8 bf[4];
#pragma unroll
        for (int c = 0; c < 4; c++)
            bf[c] = *(const short8*)&B_lds[c * 16 + mcol][quad * 8];

#pragma unroll
        for (int c = 0; c < 4; c++) {
            acc[0][c] = __builtin_amdgcn_mfma_f32_16x16x32_bf16(a0, bf[c], acc[0][c], 0, 0, 0);
            acc[1][c] = __builtin_amdgcn_mfma_f32_16x16x32_bf16(a1, bf[c], acc[1][c], 0, 0, 0);
        }
        __syncthreads();
    }

#pragma unroll
    for (int t = 0; t < 2; t++)
#pragma unroll
        for (int reg = 0; reg < 4; reg++) {
            int gr = block_row + wave * 32 + t * 16 + quad * 4 + reg;
            if (gr < NNODES) {
                float sc = dinv[gr];
#pragma unroll
                for (int c = 0; c < 4; c++)
                    h1b[(size_t)gr * F_MID + c * 16 + mcol] = f2bf(acc[t][c][reg] * sc);
            }
        }
}

// ---------------------------------------------------------------------------
// agg1: 4 nodes per 256-thread block, one wave per node, lane = feature.
// ---------------------------------------------------------------------------
__global__ __launch_bounds__(256) void agg1_kernel(const unsigned short* __restrict__ h1b,
                                                   const int* __restrict__ csr_src,
                                                   const int* __restrict__ row_start,
                                                   const float* __restrict__ dinv,
                                                   const float* __restrict__ b1,
                                                   unsigned short* __restrict__ out1b) {
    int tid = threadIdx.x;
    int node = blockIdx.x * 4 + (tid >> 6);
    int lane = tid & 63;

    int s0 = row_start[node], s1 = row_start[node + 1];
    float acc = 0.f;

    int idx[8];
    int e = s0;
#pragma unroll
    for (int j = 0; j < 8; j++) {
        int p = e + j; if (p > s1 - 1) p = s1 - 1;
        idx[j] = csr_src[p];          // uniform address -> scalar load
    }
    while (e < s1) {
        int cnt = s1 - e;             // >= 1, wave-uniform
        int cidx[8];
#pragma unroll
        for (int j = 0; j < 8; j++) cidx[j] = idx[j];
        int en = e + 8;
        if (en < s1) {
#pragma unroll
            for (int j = 0; j < 8; j++) {
                int p = en + j; if (p > s1 - 1) p = s1 - 1;
                idx[j] = csr_src[p];  // prefetch next batch (scalar)
            }
        }
#pragma unroll
        for (int j = 0; j < 8; j++) {
            float v = bf2f(h1b[(size_t)cidx[j] * F_MID + lane]);
            if (j < cnt) acc += v;    // wave-uniform predicate
        }
        e = en;
    }

    float dn = dinv[node];
    float v = fmaxf(acc * dn + b1[lane], 0.f);
    out1b[(size_t)node * F_MID + lane] = f2bf(v);
}

// ---------------------------------------------------------------------------
// GEMM2 (bf16 MFMA, no LDS): h2b[100000,48](bf16) = (out1 @ W2pad) * dinv[row]
// ---------------------------------------------------------------------------
__global__ __launch_bounds__(256) void gemm2_kernel(const unsigned short* __restrict__ out1b,
                                                    const unsigned short* __restrict__ W2T,
                                                    const float* __restrict__ dinv,
                                                    unsigned short* __restrict__ h2b) {
    int tid = threadIdx.x;
    int wave = tid >> 6;
    int lane = tid & 63;
    int n0 = blockIdx.x * 64 + wave * 16;     // 16 nodes per wave
    int m = lane & 15, quad = lane >> 4;

    int arow = n0 + m; if (arow >= NNODES) arow = NNODES - 1;

    f32x4 acc[3];
#pragma unroll
    for (int c = 0; c < 3; c++) { f32x4 z = {0.f, 0.f, 0.f, 0.f}; acc[c] = z; }

#pragma unroll
    for (int t = 0; t < 2; t++) {
        short8 a = *(const short8*)&out1b[(size_t)arow * F_MID + t * 32 + quad * 8];
#pragma unroll
        for (int c = 0; c < 3; c++) {
            short8 b = *(const short8*)&W2T[(size_t)(c * 16 + m) * F_MID + t * 32 + quad * 8];
            acc[c] = __builtin_amdgcn_mfma_f32_16x16x32_bf16(a, b, acc[c], 0, 0, 0);
        }
    }

#pragma unroll
    for (int reg = 0; reg < 4; reg++) {
        int gr = n0 + quad * 4 + reg;
        if (gr < NNODES) {
            float dn = dinv[gr];
#pragma unroll
            for (int c = 0; c < 3; c++)
                h2b[(size_t)gr * H2S + c * 16 + m] = f2bf(acc[c][reg] * dn);
        }
    }
}

// ---------------------------------------------------------------------------
// agg2 + bias + log_softmax: 4 nodes/block, lane = class.
// ---------------------------------------------------------------------------
__global__ __launch_bounds__(256) void agg2_softmax_kernel(const unsigned short* __restrict__ h2b,
                                                           const int* __restrict__ csr_src,
                                                           const int* __restrict__ row_start,
                                                           const float* __restrict__ dinv,
                                                           const float* __restrict__ b2,
                                                           float* __restrict__ out) {
    int tid = threadIdx.x;
    int node = blockIdx.x * 4 + (tid >> 6);
    int lane = tid & 63;
    int cl = (lane < H2S) ? lane : 0;

    int s0 = row_start[node], s1 = row_start[node + 1];
    float acc = 0.f;

    int idx[8];
    int e = s0;
#pragma unroll
    for (int j = 0; j < 8; j++) {
        int p = e + j; if (p > s1 - 1) p = s1 - 1;
        idx[j] = csr_src[p];
    }
    while (e < s1) {
        int cnt = s1 - e;
        int cidx[8];
#pragma unroll
        for (int j = 0; j < 8; j++) cidx[j] = idx[j];
        int en = e + 8;
        if (en < s1) {
#pragma unroll
            for (int j = 0; j < 8; j++) {
                int p = en + j; if (p > s1 - 1) p = s1 - 1;
                idx[j] = csr_src[p];
            }
        }
#pragma unroll
        for (int j = 0; j < 8; j++) {
            float v = bf2f(h2b[(size_t)cidx[j] * H2S + cl]);
            if (j < cnt) acc += v;
        }
        e = en;
    }

    float dn = dinv[node];
    bool act = (lane < F_OUT);
    float z = act ? (acc * dn + b2[cl]) : -3.4e38f;
    float m = z;
#pragma unroll
    for (int off = 1; off < 64; off <<= 1) m = fmaxf(m, __shfl_xor(m, off, 64));
    float p = act ? __expf(z - m) : 0.f;
#pragma unroll
    for (int off = 1; off < 64; off <<= 1) p += __shfl_xor(p, off, 64);
    float lse = m + logf(p);
    if (act) out[(size_t)node * F_OUT + lane] = z - lse;
}

// ---------------------------------------------------------------------------
extern "C" void kernel_launch(void* const* d_in, const int* in_sizes, int n_in,
                              void* d_out, int out_size, void* d_ws, size_t ws_size,
                              hipStream_t stream) {
    const float* X   = (const float*)d_in[0];
    const int*   ei  = (const int*)d_in[1];
    const float* W1  = (const float*)d_in[2];
    const float* b1  = (const float*)d_in[3];
    const float* W2  = (const float*)d_in[4];
    const float* b2  = (const float*)d_in[5];
    float* out = (float*)d_out;

    const int N = NNODES;
    const int E = in_sizes[1] / 2;      // 1,600,000
    const int TOTAL = E + N;
    const int* srcv = ei;
    const int* dstv = ei + E;

    char* p = (char*)d_ws;
    auto carve = [&](size_t bytes) {
        void* r = (void*)p;
        p += (bytes + 255) & ~(size_t)255;
        return r;
    };
    int*   bcnt      = (int*)carve((size_t)NBUCK * 4);
    int*   bstart    = (int*)carve((size_t)(NBUCK + 1) * 4);
    int*   bcur      = (int*)carve((size_t)NBUCK * 4);
    int*   stage     = (int*)carve((size_t)E * 4);
    int*   row_start = (int*)carve((size_t)(N + 1) * 4);
    int*   csr_src   = (int*)carve((size_t)TOTAL * 4);
    float* dinv      = (float*)carve((size_t)N * 4);
    unsigned short* W1T  = (unsigned short*)carve((size_t)F_MID * KPAD * 2);
    unsigned short* W2T  = (unsigned short*)carve((size_t)H2S * F_MID * 2);
    unsigned short* h1b  = (unsigned short*)carve((size_t)N * F_MID * 2);
    unsigned short* out1b= (unsigned short*)carve((size_t)N * F_MID * 2);
    unsigned short* h2b  = (unsigned short*)carve((size_t)N * H2S * 2);
    (void)ws_size; (void)n_in; (void)out_size;

    const int GB = (E + EPB - 1) / EPB;   // 196

    hipMemsetAsync(bcnt, 0, (size_t)NBUCK * 4, stream);
    bucket_count<<<GB, 256, 0, stream>>>(dstv, bcnt, E);
    bucket_scan<<<1, 1024, 0, stream>>>(bcnt, bstart, bcur, E);
    bucket_scatter<<<GB, 256, 0, stream>>>(srcv, dstv, bcur, stage, E);
    bucket_fill<<<NBUCK, 256, 0, stream>>>(stage, bstart, row_start, dinv, csr_src, E);

    w1t_prep<<<(F_MID * KPAD + 255) / 256, 256, 0, stream>>>(W1, W1T);
    w2t_prep<<<(H2S * F_MID + 255) / 256, 256, 0, stream>>>(W2, W2T);

    gemm1_kernel<<<(N + 127) / 128, 256, 0, stream>>>(X, W1T, dinv, h1b);
    agg1_kernel<<<N / 4, 256, 0, stream>>>(h1b, csr_src, row_start, dinv, b1, out1b);
    gemm2_kernel<<<(N + 63) / 64, 256, 0, stream>>>(out1b, W2T, dinv, h2b);
    agg2_softmax_kernel<<<N / 4, 256, 0, stream>>>(h2b, csr_src, row_start, dinv, b2, out);
}